// Round 1
// 1897.058 us; speedup vs baseline: 1.5335x; 1.5335x over previous
//
#include <hip/hip_runtime.h>
#include <hip/hip_bf16.h>
#include <math.h>

typedef unsigned short u16;
typedef __hip_bfloat16 bf16;
typedef __bf16 bf16x8 __attribute__((ext_vector_type(8)));
typedef float f32x4 __attribute__((ext_vector_type(4)));

#define B_DIM 2048
#define Z_DIM 512
#define H_DIM 384
#define G_DIM 1536   // 4H
#define T_FRM 32
#define N_STEP 31
#define W_RES 0.2f
#define FC_ROWS (B_DIM * N_STEP)   // 63488
#define FC_CHUNK 8192

__device__ __forceinline__ u16 f2b(float f) {
    bf16 h = __float2bfloat16(f);
    return __builtin_bit_cast(u16, h);
}
__device__ __forceinline__ float sigm(float x) { return 1.f / (1.f + __expf(-x)); }

typedef const __attribute__((address_space(1))) void* gas1_t;
typedef __attribute__((address_space(3))) void* las3_t;

__device__ __forceinline__ void gld_lds16(const void* g, void* l) {
    // async global->LDS, 16B per lane; HW dest = wave-uniform base + lane*16
    __builtin_amdgcn_global_load_lds((gas1_t)g, (las3_t)l, 16, 0, 0);
}

// 128x128 C-tile, 256 threads (4 waves, 2x2), mfma_f32_16x16x32_bf16, BK=32.
// A: [M,K] bf16 row-major (lda), rows at arow0.
// B: [N,K] bf16 row-major (ldb) -> computes A@B^T tile.
__device__ __forceinline__ void gemm_seg(const u16* __restrict__ A, int lda,
                                         const u16* __restrict__ B, int ldb,
                                         int arow0, int bcol0, int kch,
                                         u16* Asm, u16* Bsm, f32x4 acc[4][4])
{
    const int tid  = threadIdx.x;
    const int lane = tid & 63;
    const int wr   = ((tid >> 7) & 1) * 64;   // wave row offset
    const int wc   = ((tid >> 6) & 1) * 64;   // wave col offset
    const int l15  = lane & 15;
    const int q    = lane >> 4;
    const int srow = tid >> 2;                // staging: 4 lanes/row, 8 elems each
    const int sk   = (tid & 3) * 8;
    const u16* Ab = A + (size_t)(arow0 + srow) * lda + sk;
    const u16* Bb = B + (size_t)(bcol0 + srow) * ldb + sk;
    const size_t rstepA = (size_t)64 * lda;
    const size_t rstepB = (size_t)64 * ldb;
    u16* Al0 = Asm + tid * 8;
    u16* Bl0 = Bsm + tid * 8;

    for (int kt = 0; kt < kch; ++kt) {
        const int ko = kt * 32;
        gld_lds16(Ab + ko,          Al0);
        gld_lds16(Ab + rstepA + ko, Al0 + 2048);
        gld_lds16(Bb + ko,          Bl0);
        gld_lds16(Bb + rstepB + ko, Bl0 + 2048);
        __syncthreads();   // drains vmcnt -> LDS tiles ready
        bf16x8 av[4], bv[4];
#pragma unroll
        for (int i = 0; i < 4; ++i) {
            av[i] = *(const bf16x8*)(Asm + (wr + i * 16 + l15) * 32 + q * 8);
            bv[i] = *(const bf16x8*)(Bsm + (wc + i * 16 + l15) * 32 + q * 8);
        }
#pragma unroll
        for (int i = 0; i < 4; ++i)
#pragma unroll
            for (int j = 0; j < 4; ++j)
                acc[i][j] = __builtin_amdgcn_mfma_f32_16x16x32_bf16(av[i], bv[j], acc[i][j], 0, 0, 0);
        __syncthreads();   // all waves done reading before next stage
    }
}

// Fused gates GEMM + LSTM cell. Gate weights are ROW-PERMUTED so permuted col
// p = (u/16)*64 + g*16 + (u%16) holds gate g of unit u. With the 2x2 wave
// layout each thread's acc[i][0..3] are exactly {i,f,g,o} of one unit ->
// LSTM cell applied in registers; the [2048,1536] gates buffer never exists.
// h is double-buffered by the caller (epilogue writes h while other blocks
// still stage h as the k2 GEMM operand).
__global__ __launch_bounds__(256, 2) void k_gates_lstm(
    const u16* __restrict__ A1, const u16* __restrict__ B1, int ld1, int k1,
    const u16* __restrict__ A2, const u16* __restrict__ B2, int lda2, int ldb2, int k2,
    const float* __restrict__ bp,      // permuted combined bias [1536]
    float* __restrict__ c_fp, u16* __restrict__ h_out,
    u16* __restrict__ hcs, int s, int czero)
{
    __shared__ __attribute__((aligned(16))) u16 Asm[128 * 32];
    __shared__ __attribute__((aligned(16))) u16 Bsm[128 * 32];
    f32x4 acc[4][4];
    const f32x4 z4 = {0.f, 0.f, 0.f, 0.f};
#pragma unroll
    for (int i = 0; i < 4; ++i)
#pragma unroll
        for (int j = 0; j < 4; ++j) acc[i][j] = z4;

    const int row0 = blockIdx.x * 128;
    const int col0 = blockIdx.y * 128;
    gemm_seg(A1, ld1, B1, ld1, row0, col0, k1, Asm, Bsm, acc);
    if (k2 > 0) gemm_seg(A2, lda2, B2, ldb2, row0, col0, k2, Asm, Bsm, acc);

    const int lane = threadIdx.x & 63;
    const int wr = ((threadIdx.x >> 7) & 1) * 64;
    const int wc = ((threadIdx.x >> 6) & 1) * 64;
    const int l15 = lane & 15;
    const int q4 = (lane >> 4) * 4;
    const int cbase = col0 + wc;                 // multiple of 64
    const int u = ((cbase >> 6) << 4) + l15;     // hidden unit owned by this thread
    const float bg0 = bp[cbase + l15];
    const float bg1 = bp[cbase + 16 + l15];
    const float bg2 = bp[cbase + 32 + l15];
    const float bg3 = bp[cbase + 48 + l15];
#pragma unroll
    for (int i = 0; i < 4; ++i) {
        const int row = row0 + wr + i * 16 + q4;
#pragma unroll
        for (int r = 0; r < 4; ++r) {
            const int rr = row + r;
            const size_t ci = (size_t)rr * H_DIM + u;
            const float gi = acc[i][0][r] + bg0;
            const float gf = acc[i][1][r] + bg1;
            const float gg = acc[i][2][r] + bg2;
            const float go = acc[i][3][r] + bg3;
            const float c  = czero ? 0.f : c_fp[ci];
            const float c2 = sigm(gf) * c + sigm(gi) * tanhf(gg);
            const float h2 = sigm(go) * tanhf(c2);
            c_fp[ci] = c2;
            h_out[ci] = f2b(h2);
            if (s >= 0) {
                u16* hr = hcs + ((size_t)rr * N_STEP + s) * (2 * H_DIM);
                hr[u]         = f2b(h2);
                hr[H_DIM + u] = f2b(c2);
            }
        }
    }
}

// out_new = out + 0.2*tanh(h2@wT^T + b). 64x64 tiles -> grid (32,8) = 256
// blocks (full chip; the old 128^2 grid used only 64 of 256 CUs).
__global__ __launch_bounds__(256, 2) void k_out(
    const u16* __restrict__ hbf, const u16* __restrict__ wT, const float* __restrict__ bias,
    float* __restrict__ out_fp, u16* __restrict__ out_bf,
    float* __restrict__ outsec, float* __restrict__ esec, int ts)
{
    __shared__ __attribute__((aligned(16))) u16 Asm[64 * 32];
    __shared__ __attribute__((aligned(16))) u16 Bsm[64 * 32];
    f32x4 acc[2][2];
    const f32x4 z4 = {0.f, 0.f, 0.f, 0.f};
#pragma unroll
    for (int i = 0; i < 2; ++i)
#pragma unroll
        for (int j = 0; j < 2; ++j) acc[i][j] = z4;

    const int tid  = threadIdx.x;
    const int lane = tid & 63;
    const int wr   = ((tid >> 7) & 1) * 32;
    const int wc   = ((tid >> 6) & 1) * 32;
    const int l15  = lane & 15;
    const int q    = lane >> 4;
    const int srow = tid >> 2;
    const int sk   = (tid & 3) * 8;
    const int row0 = blockIdx.x * 64;
    const int col0 = blockIdx.y * 64;
    const u16* Ab = hbf + (size_t)(row0 + srow) * H_DIM + sk;
    const u16* Bb = wT  + (size_t)(col0 + srow) * H_DIM + sk;
    u16* Al = Asm + tid * 8;
    u16* Bl = Bsm + tid * 8;

    for (int kt = 0; kt < H_DIM / 32; ++kt) {
        const int ko = kt * 32;
        gld_lds16(Ab + ko, Al);
        gld_lds16(Bb + ko, Bl);
        __syncthreads();
        bf16x8 av[2], bv[2];
#pragma unroll
        for (int i = 0; i < 2; ++i) {
            av[i] = *(const bf16x8*)(Asm + (wr + i * 16 + l15) * 32 + q * 8);
            bv[i] = *(const bf16x8*)(Bsm + (wc + i * 16 + l15) * 32 + q * 8);
        }
#pragma unroll
        for (int i = 0; i < 2; ++i)
#pragma unroll
            for (int j = 0; j < 2; ++j)
                acc[i][j] = __builtin_amdgcn_mfma_f32_16x16x32_bf16(av[i], bv[j], acc[i][j], 0, 0, 0);
        __syncthreads();
    }

    const int q4 = q * 4;
#pragma unroll
    for (int j = 0; j < 2; ++j) {
        const int col = col0 + wc + j * 16 + l15;
        const float bv = bias[col];
#pragma unroll
        for (int i = 0; i < 2; ++i) {
            const int row = row0 + wr + i * 16 + q4;
#pragma unroll
            for (int r = 0; r < 2 * 2; ++r) {
                const int rr = row + r;
                const size_t idx = (size_t)rr * Z_DIM + col;
                const float v = acc[i][j][r] + bv;
                const float onew = out_fp[idx] + W_RES * tanhf(v);
                out_fp[idx] = onew;
                out_bf[idx] = f2b(onew);
                outsec[((size_t)rr * T_FRM + ts) * Z_DIM + col] = onew;
                if (ts <= 30)
                    esec[((size_t)rr * N_STEP + ts) * Z_DIM + col] = onew;
            }
        }
    }
}

// fc1 (batched over all steps, per M-chunk): t1 = relu(hcs_all @ fc1w^T + fc1b)
__global__ __launch_bounds__(256, 2) void k_fc1(
    const u16* __restrict__ A, const u16* __restrict__ B, const float* __restrict__ bias,
    u16* __restrict__ C)
{
    __shared__ __attribute__((aligned(16))) u16 Asm[128 * 32];
    __shared__ __attribute__((aligned(16))) u16 Bsm[128 * 32];
    f32x4 acc[4][4];
    const f32x4 z4 = {0.f, 0.f, 0.f, 0.f};
#pragma unroll
    for (int i = 0; i < 4; ++i)
#pragma unroll
        for (int j = 0; j < 4; ++j) acc[i][j] = z4;

    const int row0 = blockIdx.x * 128;
    const int col0 = blockIdx.y * 128;
    gemm_seg(A, 2 * H_DIM, B, 2 * H_DIM, row0, col0, 2 * H_DIM / 32, Asm, Bsm, acc);

    const int lane = threadIdx.x & 63;
    const int wr = ((threadIdx.x >> 7) & 1) * 64;
    const int wc = ((threadIdx.x >> 6) & 1) * 64;
    const int l15 = lane & 15;
    const int q4 = (lane >> 4) * 4;
#pragma unroll
    for (int j = 0; j < 4; ++j) {
        const int col = col0 + wc + j * 16 + l15;
        const float bv = bias[col];
#pragma unroll
        for (int i = 0; i < 4; ++i) {
            const int row = row0 + wr + i * 16 + q4;
#pragma unroll
            for (int r = 0; r < 4; ++r)
                C[(size_t)(row + r) * Z_DIM + col] = f2b(fmaxf(acc[i][j][r] + bv, 0.f));
        }
    }
}

// fc2 (batched, per M-chunk): erec rows = t1 @ fc2w^T + fc2b, contiguous [rows,512]
__global__ __launch_bounds__(256, 2) void k_fc2(
    const u16* __restrict__ A, const u16* __restrict__ B, const float* __restrict__ bias,
    float* __restrict__ C)
{
    __shared__ __attribute__((aligned(16))) u16 Asm[128 * 32];
    __shared__ __attribute__((aligned(16))) u16 Bsm[128 * 32];
    f32x4 acc[4][4];
    const f32x4 z4 = {0.f, 0.f, 0.f, 0.f};
#pragma unroll
    for (int i = 0; i < 4; ++i)
#pragma unroll
        for (int j = 0; j < 4; ++j) acc[i][j] = z4;

    const int row0 = blockIdx.x * 128;
    const int col0 = blockIdx.y * 128;
    gemm_seg(A, Z_DIM, B, Z_DIM, row0, col0, Z_DIM / 32, Asm, Bsm, acc);

    const int lane = threadIdx.x & 63;
    const int wr = ((threadIdx.x >> 7) & 1) * 64;
    const int wc = ((threadIdx.x >> 6) & 1) * 64;
    const int l15 = lane & 15;
    const int q4 = (lane >> 4) * 4;
#pragma unroll
    for (int j = 0; j < 4; ++j) {
        const int col = col0 + wc + j * 16 + l15;
        const float bv = bias[col];
#pragma unroll
        for (int i = 0; i < 4; ++i) {
            const int row = row0 + wr + i * 16 + q4;
#pragma unroll
            for (int r = 0; r < 4; ++r)
                C[(size_t)(row + r) * Z_DIM + col] = acc[i][j][r] + bv;
        }
    }
}

// fp32 -> bf16 elementwise convert (one-shot, fc weights)
__global__ void k_cvt(const float* __restrict__ src, u16* __restrict__ dst, int n)
{
    const int i = blockIdx.x * 256 + threadIdx.x;
    if (i < n) dst[i] = f2b(src[i]);
}

// fp32 -> bf16 with gate-row permutation: dst row p = src row g*384+u where
// p = (u/16)*64 + g*16 + (u%16)  <=>  g=(p>>4)&3, u=(p>>6)*16+(p&15)
__global__ void k_cvtp(const float* __restrict__ src, u16* __restrict__ dst, int K)
{
    const int i = blockIdx.x * 256 + threadIdx.x;   // < 1536*K
    const int p = i / K;
    const int k = i - p * K;
    const int u = ((p >> 6) << 4) | (p & 15);
    const int g = (p >> 4) & 3;
    dst[i] = f2b(src[(size_t)(g * H_DIM + u) * K + k]);
}

// permuted combined bias: bp[p] = b1[orig(p)] + b2[orig(p)]
__global__ void k_biasp(const float* __restrict__ b1, const float* __restrict__ b2,
                        float* __restrict__ bp)
{
    const int p = blockIdx.x * 256 + threadIdx.x;   // < 1536
    const int u = ((p >> 6) << 4) | (p & 15);
    const int g = (p >> 4) & 3;
    bp[p] = b1[g * H_DIM + u] + b2[g * H_DIM + u];
}

// init: out_fp = z, out_bf = bf16(z); out time-slice 0 = z; e time-slice 0 = z
__global__ void k_init(const float* __restrict__ z, float* __restrict__ out_fp,
                       u16* __restrict__ out_bf, float* __restrict__ outsec,
                       float* __restrict__ esec)
{
    const int i = blockIdx.x * 256 + threadIdx.x;   // < 2048*512
    const int m = i >> 9;
    const int n = i & 511;
    const float zv = z[i];
    out_fp[i] = zv;
    out_bf[i] = f2b(zv);
    outsec[((size_t)m * T_FRM) * Z_DIM + n] = zv;
    esec[((size_t)m * N_STEP) * Z_DIM + n] = zv;
}

// wT[n][k] = bf16(w[k][n])  (w: fp32 [384,512] -> wT: bf16 [512,384])
__global__ void k_trw(const float* __restrict__ w, u16* __restrict__ wT)
{
    const int i = blockIdx.x * 256 + threadIdx.x;   // < 384*512
    const int k = i >> 9;
    const int n = i & 511;
    wT[(size_t)n * H_DIM + k] = f2b(w[i]);
}

extern "C" void kernel_launch(void* const* d_in, const int* in_sizes, int n_in,
                              void* d_out, int out_size, void* d_ws, size_t ws_size,
                              hipStream_t stream)
{
    const float* z       = (const float*)d_in[0];
    const float* Wih_enc = (const float*)d_in[1];
    // d_in[2] = Whh_enc: multiplied by h=0 in the encoder -> unused
    const float* bih_enc = (const float*)d_in[3];
    const float* bhh_enc = (const float*)d_in[4];
    const float* Wih  = (const float*)d_in[5];
    const float* Whh  = (const float*)d_in[6];
    const float* bih  = (const float*)d_in[7];
    const float* bhh  = (const float*)d_in[8];
    const float* w    = (const float*)d_in[9];
    const float* bvec = (const float*)d_in[10];
    const float* fc1w = (const float*)d_in[11];
    const float* fc1b = (const float*)d_in[12];
    const float* fc2w = (const float*)d_in[13];
    const float* fc2b = (const float*)d_in[14];
    // n_frame fixed at 32 (cannot read device scalar during graph capture)

    float* outsec = (float*)d_out;                                  // [2048*32, 512]
    float* esec   = outsec + (size_t)B_DIM * T_FRM * Z_DIM;         // [2048*31, 512]
    float* erec   = esec + (size_t)B_DIM * N_STEP * Z_DIM;          // [2048*31, 512]

    // hcs_all [63488, 768] bf16 staged INSIDE the erec output region at byte
    // offset FC_ROWS*512 (= erec_bytes - hcs_bytes). Safety: after fc-chunk c
    // (rows < end) writes erec, the clobbered hcs rows are
    // < (end*2048 - FC_ROWS*512)/1536 <= end  (since end <= FC_ROWS), i.e.
    // only rows already consumed by fc1 of this or earlier chunks.
    u16* hcs_all = (u16*)((char*)erec + (size_t)FC_ROWS * 512);

    // Fixed workspace plan, ~27 MiB total.
    char* ws = (char*)d_ws;
    size_t off = 0;
    auto alloc = [&](size_t bytes) -> char* {
        char* p = ws + off;
        off += (bytes + 255) & ~(size_t)255;
        return p;
    };
    float* c_fp    = (float*)alloc((size_t)B_DIM * H_DIM * 4);       //  3.1 MB
    float* out_fp  = (float*)alloc((size_t)B_DIM * Z_DIM * 4);       //  4.2 MB
    u16*   out_bf  = (u16*)  alloc((size_t)B_DIM * Z_DIM * 2);       //  2.1 MB
    u16*   hb0     = (u16*)  alloc((size_t)B_DIM * H_DIM * 2);       //  1.6 MB
    u16*   hb1     = (u16*)  alloc((size_t)B_DIM * H_DIM * 2);       //  1.6 MB
    u16*   wT      = (u16*)  alloc((size_t)Z_DIM * H_DIM * 2);       //  0.4 MB
    u16*   t1      = (u16*)  alloc((size_t)FC_CHUNK * Z_DIM * 2);    //  8.4 MB
    u16*   Wenc_bf = (u16*)  alloc((size_t)G_DIM * Z_DIM * 2);       //  1.6 MB
    u16*   Wih_bf  = (u16*)  alloc((size_t)G_DIM * Z_DIM * 2);       //  1.6 MB
    u16*   Whh_bf  = (u16*)  alloc((size_t)G_DIM * H_DIM * 2);       //  1.2 MB
    u16*   fc1w_bf = (u16*)  alloc((size_t)Z_DIM * 2 * H_DIM * 2);   //  0.8 MB
    u16*   fc2w_bf = (u16*)  alloc((size_t)Z_DIM * Z_DIM * 2);       //  0.5 MB
    float* bpe     = (float*)alloc((size_t)G_DIM * 4);               //  6 KB
    float* bpd     = (float*)alloc((size_t)G_DIM * 4);               //  6 KB
    u16*   hbuf[2] = {hb0, hb1};

    const dim3 blk(256);
    // one-shot weight conversions (gate weights row-permuted for fused LSTM)
    k_cvtp<<<G_DIM * Z_DIM / 256, blk, 0, stream>>>(Wih_enc, Wenc_bf, Z_DIM);
    k_cvtp<<<G_DIM * Z_DIM / 256, blk, 0, stream>>>(Wih, Wih_bf, Z_DIM);
    k_cvtp<<<G_DIM * H_DIM / 256, blk, 0, stream>>>(Whh, Whh_bf, H_DIM);
    k_biasp<<<G_DIM / 256, blk, 0, stream>>>(bih_enc, bhh_enc, bpe);
    k_biasp<<<G_DIM / 256, blk, 0, stream>>>(bih, bhh, bpd);
    k_cvt<<<Z_DIM * 2 * H_DIM / 256, blk, 0, stream>>>(fc1w, fc1w_bf, Z_DIM * 2 * H_DIM);
    k_cvt<<<Z_DIM * Z_DIM / 256, blk, 0, stream>>>(fc2w, fc2w_bf, Z_DIM * Z_DIM);
    k_trw<<<H_DIM * Z_DIM / 256, blk, 0, stream>>>(w, wT);
    k_init<<<B_DIM * Z_DIM / 256, blk, 0, stream>>>(z, out_fp, out_bf, outsec, esec);

    // encoder: gates = z @ Wih_enc^T + (bih_enc+bhh_enc); c=0; no hcs record
    k_gates_lstm<<<dim3(16, 12), blk, 0, stream>>>(
        out_bf, Wenc_bf, Z_DIM, Z_DIM / 32,
        nullptr, nullptr, 0, 0, 0,
        bpe, c_fp, hbuf[0], nullptr, -1, 1);

    for (int s = 0; s < N_STEP; ++s) {
        const u16* hp = hbuf[s & 1];
        u16*       hn = hbuf[(s + 1) & 1];
        k_gates_lstm<<<dim3(16, 12), blk, 0, stream>>>(
            out_bf, Wih_bf, Z_DIM, Z_DIM / 32,
            hp, Whh_bf, H_DIM, H_DIM, H_DIM / 32,
            bpd, c_fp, hn, hcs_all, s, 0);
        k_out<<<dim3(32, 8), blk, 0, stream>>>(hn, wT, bvec, out_fp, out_bf,
                                               outsec, esec, s + 1);
    }

    // batched e_rec = relu(hcs_all @ fc1w^T + fc1b) @ fc2w^T + fc2b, chunked M
    for (int r0 = 0; r0 < FC_ROWS; r0 += FC_CHUNK) {
        const int rows = (FC_ROWS - r0 < FC_CHUNK) ? (FC_ROWS - r0) : FC_CHUNK;
        k_fc1<<<dim3(rows / 128, 4), blk, 0, stream>>>(
            hcs_all + (size_t)r0 * (2 * H_DIM), fc1w_bf, fc1b, t1);
        k_fc2<<<dim3(rows / 128, 4), blk, 0, stream>>>(
            t1, fc2w_bf, fc2b, erec + (size_t)r0 * Z_DIM);
    }
}

// Round 2
// 1446.957 us; speedup vs baseline: 2.0105x; 1.3111x over previous
//
#include <hip/hip_runtime.h>
#include <hip/hip_bf16.h>
#include <math.h>

typedef unsigned short u16;
typedef __hip_bfloat16 bf16;
typedef __bf16 bf16x8 __attribute__((ext_vector_type(8)));
typedef float f32x4 __attribute__((ext_vector_type(4)));

#define B_DIM 2048
#define Z_DIM 512
#define H_DIM 384
#define G_DIM 1536   // 4H
#define T_FRM 32
#define N_STEP 31
#define W_RES 0.2f
#define FC_ROWS (B_DIM * N_STEP)   // 63488
#define FC_CHUNK 16384

__device__ __forceinline__ u16 f2b(float f) {
    bf16 h = __float2bfloat16(f);
    return __builtin_bit_cast(u16, h);
}
__device__ __forceinline__ float sigm(float x) { return 1.f / (1.f + __expf(-x)); }

typedef const __attribute__((address_space(1))) void* gas1_t;
typedef __attribute__((address_space(3))) void* las3_t;

__device__ __forceinline__ void gld_lds16(const void* g, void* l) {
    // async global->LDS, 16B per lane; HW dest = wave-uniform base + lane*16
    __builtin_amdgcn_global_load_lds((gas1_t)g, (las3_t)l, 16, 0, 0);
}

// ---------------------------------------------------------------------------
// LDS swizzle (both-sides, rule #21): rows are 64B (32 u16) = 4 x 16B slots.
// global_load_lds writes linearly (lane*16B), so we pre-swizzle the SOURCE:
// lane l stages global chunk (l&3)^((l>>3)&3) of row l>>2, making
//   LDS[row][slot] = global[row][slot ^ ((row>>1)&3)].
// Fragment reads use slot = q ^ ((row>>1)&3); for a 16-lane b128 read this
// covers all 8 16B bank-groups with 2 lanes each -> conflict-free (m136).
// ---------------------------------------------------------------------------

// 64x64 C-tile, 256 threads = 4 waves; wave wv owns rows [wv*16, wv*16+16) x
// all 64 cols. A: [M,K] bf16 row-major, B: [N,K] row-major -> A@B^T tile.
// acc[j]: col = col0 + j*16 + (lane&15), row = row0 + wv*16 + (lane>>4)*4 + r.
__device__ __forceinline__ void gemm64(const u16* __restrict__ A, int lda,
                                       const u16* __restrict__ B, int ldb,
                                       int arow0, int bcol0, int kch,
                                       u16* Asm, u16* Bsm, f32x4 acc[4])
{
    const int tid  = threadIdx.x;
    const int lane = tid & 63;
    const int wv   = tid >> 6;
    const int l15  = lane & 15;
    const int q    = lane >> 4;
    const int srow = tid >> 2;                       // 4 lanes/row, 8 elems each
    const int sk   = ((tid & 3) ^ ((tid >> 3) & 3)) * 8;   // pre-swizzled source
    const u16* Ab = A + (size_t)(arow0 + srow) * lda + sk;
    const u16* Bb = B + (size_t)(bcol0 + srow) * ldb + sk;
    u16* Al0 = Asm + tid * 8;
    u16* Bl0 = Bsm + tid * 8;
    const int swz  = (q ^ ((l15 >> 1) & 3)) * 8;     // swizzled read slot
    const int aoff = (wv * 16 + l15) * 32 + swz;

    for (int kt = 0; kt < kch; ++kt) {
        const int ko = kt * 32;
        gld_lds16(Ab + ko, Al0);
        gld_lds16(Bb + ko, Bl0);
        __syncthreads();   // drains vmcnt -> LDS tiles ready
        bf16x8 av = *(const bf16x8*)(Asm + aoff);
        bf16x8 bv[4];
#pragma unroll
        for (int j = 0; j < 4; ++j)
            bv[j] = *(const bf16x8*)(Bsm + (j * 16 + l15) * 32 + swz);
#pragma unroll
        for (int j = 0; j < 4; ++j)
            acc[j] = __builtin_amdgcn_mfma_f32_16x16x32_bf16(av, bv[j], acc[j], 0, 0, 0);
        __syncthreads();   // all waves done reading before next stage
    }
}

// 128x128 C-tile, 256 threads (4 waves, 2x2), BK=32 — used by the batched fc
// GEMMs where M is large. Same swizzle as gemm64.
__device__ __forceinline__ void gemm_seg(const u16* __restrict__ A, int lda,
                                         const u16* __restrict__ B, int ldb,
                                         int arow0, int bcol0, int kch,
                                         u16* Asm, u16* Bsm, f32x4 acc[4][4])
{
    const int tid  = threadIdx.x;
    const int lane = tid & 63;
    const int wr   = ((tid >> 7) & 1) * 64;   // wave row offset
    const int wc   = ((tid >> 6) & 1) * 64;   // wave col offset
    const int l15  = lane & 15;
    const int q    = lane >> 4;
    const int srow = tid >> 2;
    const int sk   = ((tid & 3) ^ ((tid >> 3) & 3)) * 8;   // pre-swizzled source
    const u16* Ab = A + (size_t)(arow0 + srow) * lda + sk;
    const u16* Bb = B + (size_t)(bcol0 + srow) * ldb + sk;
    const size_t rstepA = (size_t)64 * lda;
    const size_t rstepB = (size_t)64 * ldb;
    u16* Al0 = Asm + tid * 8;
    u16* Bl0 = Bsm + tid * 8;
    const int swz = (q ^ ((l15 >> 1) & 3)) * 8;

    for (int kt = 0; kt < kch; ++kt) {
        const int ko = kt * 32;
        gld_lds16(Ab + ko,          Al0);
        gld_lds16(Ab + rstepA + ko, Al0 + 2048);
        gld_lds16(Bb + ko,          Bl0);
        gld_lds16(Bb + rstepB + ko, Bl0 + 2048);
        __syncthreads();
        bf16x8 av[4], bv[4];
#pragma unroll
        for (int i = 0; i < 4; ++i) {
            av[i] = *(const bf16x8*)(Asm + (wr + i * 16 + l15) * 32 + swz);
            bv[i] = *(const bf16x8*)(Bsm + (wc + i * 16 + l15) * 32 + swz);
        }
#pragma unroll
        for (int i = 0; i < 4; ++i)
#pragma unroll
            for (int j = 0; j < 4; ++j)
                acc[i][j] = __builtin_amdgcn_mfma_f32_16x16x32_bf16(av[i], bv[j], acc[i][j], 0, 0, 0);
        __syncthreads();
    }
}

// Fused gates GEMM + LSTM cell, 64x64 tiles -> grid (32,24) = 768 blocks =
// 3 blocks/CU (12 waves/CU for implicit MFMA/stage overlap). Gate weights are
// ROW-PERMUTED: permuted col p = (u/16)*64 + g*16 + (u%16). With 64-col tiles
// each thread's acc[0..3] are exactly {i,f,g,o} of unit blockIdx.y*16 + l15.
__global__ __launch_bounds__(256, 4) void k_gates_lstm(
    const u16* __restrict__ A1, const u16* __restrict__ B1, int ld1, int k1,
    const u16* __restrict__ A2, const u16* __restrict__ B2, int lda2, int ldb2, int k2,
    const float* __restrict__ bp,      // permuted combined bias [1536]
    float* __restrict__ c_fp, u16* __restrict__ h_out,
    u16* __restrict__ hcs, int s, int czero)
{
    __shared__ __attribute__((aligned(16))) u16 Asm[64 * 32];
    __shared__ __attribute__((aligned(16))) u16 Bsm[64 * 32];
    f32x4 acc[4];
    const f32x4 z4 = {0.f, 0.f, 0.f, 0.f};
#pragma unroll
    for (int j = 0; j < 4; ++j) acc[j] = z4;

    const int row0 = blockIdx.x * 64;
    const int col0 = blockIdx.y * 64;
    gemm64(A1, ld1, B1, ld1, row0, col0, k1, Asm, Bsm, acc);
    if (k2 > 0) gemm64(A2, lda2, B2, ldb2, row0, col0, k2, Asm, Bsm, acc);

    const int lane = threadIdx.x & 63;
    const int wv   = threadIdx.x >> 6;
    const int l15  = lane & 15;
    const int q4   = (lane >> 4) * 4;
    const int u    = blockIdx.y * 16 + l15;      // hidden unit owned by this thread
    const float bg0 = bp[col0 + l15];
    const float bg1 = bp[col0 + 16 + l15];
    const float bg2 = bp[col0 + 32 + l15];
    const float bg3 = bp[col0 + 48 + l15];
#pragma unroll
    for (int r = 0; r < 4; ++r) {
        const int rr = row0 + wv * 16 + q4 + r;
        const size_t ci = (size_t)rr * H_DIM + u;
        const float gi = acc[0][r] + bg0;
        const float gf = acc[1][r] + bg1;
        const float gg = acc[2][r] + bg2;
        const float go = acc[3][r] + bg3;
        const float c  = czero ? 0.f : c_fp[ci];
        const float c2 = sigm(gf) * c + sigm(gi) * tanhf(gg);
        const float h2 = sigm(go) * tanhf(c2);
        c_fp[ci] = c2;
        h_out[ci] = f2b(h2);
        if (s >= 0) {
            u16* hr = hcs + ((size_t)rr * N_STEP + s) * (2 * H_DIM);
            hr[u]         = f2b(h2);
            hr[H_DIM + u] = f2b(c2);
        }
    }
}

// out_new = out + 0.2*tanh(h2@wT^T + b). 64x64 tiles, grid (32,8) = 256 blocks.
__global__ __launch_bounds__(256, 4) void k_out(
    const u16* __restrict__ hbf, const u16* __restrict__ wT, const float* __restrict__ bias,
    float* __restrict__ out_fp, u16* __restrict__ out_bf,
    float* __restrict__ outsec, float* __restrict__ esec, int ts)
{
    __shared__ __attribute__((aligned(16))) u16 Asm[64 * 32];
    __shared__ __attribute__((aligned(16))) u16 Bsm[64 * 32];
    f32x4 acc[4];
    const f32x4 z4 = {0.f, 0.f, 0.f, 0.f};
#pragma unroll
    for (int j = 0; j < 4; ++j) acc[j] = z4;

    const int row0 = blockIdx.x * 64;
    const int col0 = blockIdx.y * 64;
    gemm64(hbf, H_DIM, wT, H_DIM, row0, col0, H_DIM / 32, Asm, Bsm, acc);

    const int lane = threadIdx.x & 63;
    const int wv   = threadIdx.x >> 6;
    const int l15  = lane & 15;
    const int q4   = (lane >> 4) * 4;
#pragma unroll
    for (int j = 0; j < 4; ++j) {
        const int col = col0 + j * 16 + l15;
        const float bv = bias[col];
#pragma unroll
        for (int r = 0; r < 4; ++r) {
            const int rr = row0 + wv * 16 + q4 + r;
            const size_t idx = (size_t)rr * Z_DIM + col;
            const float v = acc[j][r] + bv;
            const float onew = out_fp[idx] + W_RES * tanhf(v);
            out_fp[idx] = onew;
            out_bf[idx] = f2b(onew);
            outsec[((size_t)rr * T_FRM + ts) * Z_DIM + col] = onew;
            if (ts <= 30)
                esec[((size_t)rr * N_STEP + ts) * Z_DIM + col] = onew;
        }
    }
}

// fc1 (batched over all steps, per M-chunk): t1 = relu(hcs_all @ fc1w^T + fc1b)
__global__ __launch_bounds__(256, 2) void k_fc1(
    const u16* __restrict__ A, const u16* __restrict__ B, const float* __restrict__ bias,
    u16* __restrict__ C)
{
    __shared__ __attribute__((aligned(16))) u16 Asm[128 * 32];
    __shared__ __attribute__((aligned(16))) u16 Bsm[128 * 32];
    f32x4 acc[4][4];
    const f32x4 z4 = {0.f, 0.f, 0.f, 0.f};
#pragma unroll
    for (int i = 0; i < 4; ++i)
#pragma unroll
        for (int j = 0; j < 4; ++j) acc[i][j] = z4;

    const int row0 = blockIdx.x * 128;
    const int col0 = blockIdx.y * 128;
    gemm_seg(A, 2 * H_DIM, B, 2 * H_DIM, row0, col0, 2 * H_DIM / 32, Asm, Bsm, acc);

    const int lane = threadIdx.x & 63;
    const int wr = ((threadIdx.x >> 7) & 1) * 64;
    const int wc = ((threadIdx.x >> 6) & 1) * 64;
    const int l15 = lane & 15;
    const int q4 = (lane >> 4) * 4;
#pragma unroll
    for (int j = 0; j < 4; ++j) {
        const int col = col0 + wc + j * 16 + l15;
        const float bv = bias[col];
#pragma unroll
        for (int i = 0; i < 4; ++i) {
            const int row = row0 + wr + i * 16 + q4;
#pragma unroll
            for (int r = 0; r < 4; ++r)
                C[(size_t)(row + r) * Z_DIM + col] = f2b(fmaxf(acc[i][j][r] + bv, 0.f));
        }
    }
}

// fc2 (batched, per M-chunk): erec rows = t1 @ fc2w^T + fc2b, contiguous [rows,512]
__global__ __launch_bounds__(256, 2) void k_fc2(
    const u16* __restrict__ A, const u16* __restrict__ B, const float* __restrict__ bias,
    float* __restrict__ C)
{
    __shared__ __attribute__((aligned(16))) u16 Asm[128 * 32];
    __shared__ __attribute__((aligned(16))) u16 Bsm[128 * 32];
    f32x4 acc[4][4];
    const f32x4 z4 = {0.f, 0.f, 0.f, 0.f};
#pragma unroll
    for (int i = 0; i < 4; ++i)
#pragma unroll
        for (int j = 0; j < 4; ++j) acc[i][j] = z4;

    const int row0 = blockIdx.x * 128;
    const int col0 = blockIdx.y * 128;
    gemm_seg(A, Z_DIM, B, Z_DIM, row0, col0, Z_DIM / 32, Asm, Bsm, acc);

    const int lane = threadIdx.x & 63;
    const int wr = ((threadIdx.x >> 7) & 1) * 64;
    const int wc = ((threadIdx.x >> 6) & 1) * 64;
    const int l15 = lane & 15;
    const int q4 = (lane >> 4) * 4;
#pragma unroll
    for (int j = 0; j < 4; ++j) {
        const int col = col0 + wc + j * 16 + l15;
        const float bv = bias[col];
#pragma unroll
        for (int i = 0; i < 4; ++i) {
            const int row = row0 + wr + i * 16 + q4;
#pragma unroll
            for (int r = 0; r < 4; ++r)
                C[(size_t)(row + r) * Z_DIM + col] = acc[i][j][r] + bv;
        }
    }
}

// fp32 -> bf16 elementwise convert (one-shot, fc weights)
__global__ void k_cvt(const float* __restrict__ src, u16* __restrict__ dst, int n)
{
    const int i = blockIdx.x * 256 + threadIdx.x;
    if (i < n) dst[i] = f2b(src[i]);
}

// fp32 -> bf16 with gate-row permutation: dst row p = src row g*384+u where
// p = (u/16)*64 + g*16 + (u%16)  <=>  g=(p>>4)&3, u=(p>>6)*16+(p&15)
__global__ void k_cvtp(const float* __restrict__ src, u16* __restrict__ dst, int K)
{
    const int i = blockIdx.x * 256 + threadIdx.x;   // < 1536*K
    const int p = i / K;
    const int k = i - p * K;
    const int u = ((p >> 6) << 4) | (p & 15);
    const int g = (p >> 4) & 3;
    dst[i] = f2b(src[(size_t)(g * H_DIM + u) * K + k]);
}

// permuted combined bias: bp[p] = b1[orig(p)] + b2[orig(p)]
__global__ void k_biasp(const float* __restrict__ b1, const float* __restrict__ b2,
                        float* __restrict__ bp)
{
    const int p = blockIdx.x * 256 + threadIdx.x;   // < 1536
    const int u = ((p >> 6) << 4) | (p & 15);
    const int g = (p >> 4) & 3;
    bp[p] = b1[g * H_DIM + u] + b2[g * H_DIM + u];
}

// init: out_fp = z, out_bf = bf16(z); out time-slice 0 = z; e time-slice 0 = z
__global__ void k_init(const float* __restrict__ z, float* __restrict__ out_fp,
                       u16* __restrict__ out_bf, float* __restrict__ outsec,
                       float* __restrict__ esec)
{
    const int i = blockIdx.x * 256 + threadIdx.x;   // < 2048*512
    const int m = i >> 9;
    const int n = i & 511;
    const float zv = z[i];
    out_fp[i] = zv;
    out_bf[i] = f2b(zv);
    outsec[((size_t)m * T_FRM) * Z_DIM + n] = zv;
    esec[((size_t)m * N_STEP) * Z_DIM + n] = zv;
}

// wT[n][k] = bf16(w[k][n])  (w: fp32 [384,512] -> wT: bf16 [512,384])
__global__ void k_trw(const float* __restrict__ w, u16* __restrict__ wT)
{
    const int i = blockIdx.x * 256 + threadIdx.x;   // < 384*512
    const int k = i >> 9;
    const int n = i & 511;
    wT[(size_t)n * H_DIM + k] = f2b(w[i]);
}

extern "C" void kernel_launch(void* const* d_in, const int* in_sizes, int n_in,
                              void* d_out, int out_size, void* d_ws, size_t ws_size,
                              hipStream_t stream)
{
    const float* z       = (const float*)d_in[0];
    const float* Wih_enc = (const float*)d_in[1];
    // d_in[2] = Whh_enc: multiplied by h=0 in the encoder -> unused
    const float* bih_enc = (const float*)d_in[3];
    const float* bhh_enc = (const float*)d_in[4];
    const float* Wih  = (const float*)d_in[5];
    const float* Whh  = (const float*)d_in[6];
    const float* bih  = (const float*)d_in[7];
    const float* bhh  = (const float*)d_in[8];
    const float* w    = (const float*)d_in[9];
    const float* bvec = (const float*)d_in[10];
    const float* fc1w = (const float*)d_in[11];
    const float* fc1b = (const float*)d_in[12];
    const float* fc2w = (const float*)d_in[13];
    const float* fc2b = (const float*)d_in[14];
    // n_frame fixed at 32 (cannot read device scalar during graph capture)

    float* outsec = (float*)d_out;                                  // [2048*32, 512]
    float* esec   = outsec + (size_t)B_DIM * T_FRM * Z_DIM;         // [2048*31, 512]
    float* erec   = esec + (size_t)B_DIM * N_STEP * Z_DIM;          // [2048*31, 512]

    // hcs_all [63488, 768] bf16 staged INSIDE the erec output region at byte
    // offset FC_ROWS*512 (= erec_bytes - hcs_bytes). Safety: after fc-chunk
    // (rows < end) writes erec, the clobbered hcs rows are
    // < (end*2048 - FC_ROWS*512)/1536 <= end  (since end <= FC_ROWS), i.e.
    // only rows already consumed by fc1 of this or earlier chunks.
    u16* hcs_all = (u16*)((char*)erec + (size_t)FC_ROWS * 512);

    // Fixed workspace plan, ~35 MiB total.
    char* ws = (char*)d_ws;
    size_t off = 0;
    auto alloc = [&](size_t bytes) -> char* {
        char* p = ws + off;
        off += (bytes + 255) & ~(size_t)255;
        return p;
    };
    float* c_fp    = (float*)alloc((size_t)B_DIM * H_DIM * 4);       //  3.1 MB
    float* out_fp  = (float*)alloc((size_t)B_DIM * Z_DIM * 4);       //  4.2 MB
    u16*   out_bf  = (u16*)  alloc((size_t)B_DIM * Z_DIM * 2);       //  2.1 MB
    u16*   hb0     = (u16*)  alloc((size_t)B_DIM * H_DIM * 2);       //  1.6 MB
    u16*   hb1     = (u16*)  alloc((size_t)B_DIM * H_DIM * 2);       //  1.6 MB
    u16*   wT      = (u16*)  alloc((size_t)Z_DIM * H_DIM * 2);       //  0.4 MB
    u16*   t1      = (u16*)  alloc((size_t)FC_CHUNK * Z_DIM * 2);    // 16.8 MB
    u16*   Wenc_bf = (u16*)  alloc((size_t)G_DIM * Z_DIM * 2);       //  1.6 MB
    u16*   Wih_bf  = (u16*)  alloc((size_t)G_DIM * Z_DIM * 2);       //  1.6 MB
    u16*   Whh_bf  = (u16*)  alloc((size_t)G_DIM * H_DIM * 2);       //  1.2 MB
    u16*   fc1w_bf = (u16*)  alloc((size_t)Z_DIM * 2 * H_DIM * 2);   //  0.8 MB
    u16*   fc2w_bf = (u16*)  alloc((size_t)Z_DIM * Z_DIM * 2);       //  0.5 MB
    float* bpe     = (float*)alloc((size_t)G_DIM * 4);               //  6 KB
    float* bpd     = (float*)alloc((size_t)G_DIM * 4);               //  6 KB
    u16*   hbuf[2] = {hb0, hb1};

    const dim3 blk(256);
    // one-shot weight conversions (gate weights row-permuted for fused LSTM)
    k_cvtp<<<G_DIM * Z_DIM / 256, blk, 0, stream>>>(Wih_enc, Wenc_bf, Z_DIM);
    k_cvtp<<<G_DIM * Z_DIM / 256, blk, 0, stream>>>(Wih, Wih_bf, Z_DIM);
    k_cvtp<<<G_DIM * H_DIM / 256, blk, 0, stream>>>(Whh, Whh_bf, H_DIM);
    k_biasp<<<G_DIM / 256, blk, 0, stream>>>(bih_enc, bhh_enc, bpe);
    k_biasp<<<G_DIM / 256, blk, 0, stream>>>(bih, bhh, bpd);
    k_cvt<<<Z_DIM * 2 * H_DIM / 256, blk, 0, stream>>>(fc1w, fc1w_bf, Z_DIM * 2 * H_DIM);
    k_cvt<<<Z_DIM * Z_DIM / 256, blk, 0, stream>>>(fc2w, fc2w_bf, Z_DIM * Z_DIM);
    k_trw<<<H_DIM * Z_DIM / 256, blk, 0, stream>>>(w, wT);
    k_init<<<B_DIM * Z_DIM / 256, blk, 0, stream>>>(z, out_fp, out_bf, outsec, esec);

    // encoder: gates = z @ Wih_enc^T + (bih_enc+bhh_enc); c=0; no hcs record
    k_gates_lstm<<<dim3(32, 24), blk, 0, stream>>>(
        out_bf, Wenc_bf, Z_DIM, Z_DIM / 32,
        nullptr, nullptr, 0, 0, 0,
        bpe, c_fp, hbuf[0], nullptr, -1, 1);

    for (int s = 0; s < N_STEP; ++s) {
        const u16* hp = hbuf[s & 1];
        u16*       hn = hbuf[(s + 1) & 1];
        k_gates_lstm<<<dim3(32, 24), blk, 0, stream>>>(
            out_bf, Wih_bf, Z_DIM, Z_DIM / 32,
            hp, Whh_bf, H_DIM, H_DIM, H_DIM / 32,
            bpd, c_fp, hn, hcs_all, s, 0);
        k_out<<<dim3(32, 8), blk, 0, stream>>>(hn, wT, bvec, out_fp, out_bf,
                                               outsec, esec, s + 1);
    }

    // batched e_rec = relu(hcs_all @ fc1w^T + fc1b) @ fc2w^T + fc2b, chunked M
    for (int r0 = 0; r0 < FC_ROWS; r0 += FC_CHUNK) {
        const int rows = (FC_ROWS - r0 < FC_CHUNK) ? (FC_ROWS - r0) : FC_CHUNK;
        k_fc1<<<dim3(rows / 128, 4), blk, 0, stream>>>(
            hcs_all + (size_t)r0 * (2 * H_DIM), fc1w_bf, fc1b, t1);
        k_fc2<<<dim3(rows / 128, 4), blk, 0, stream>>>(
            t1, fc2w_bf, fc2b, erec + (size_t)r0 * Z_DIM);
    }
}